// Round 13
// baseline (526.869 us; speedup 1.0000x reference)
//
#include <hip/hip_runtime.h>

typedef unsigned short u16;
typedef unsigned int u32;
typedef __bf16 bf16x8 __attribute__((ext_vector_type(8)));
typedef float f32x4 __attribute__((ext_vector_type(4)));
typedef float f32x2 __attribute__((ext_vector_type(2)));
typedef u16 u16x4 __attribute__((ext_vector_type(4)));
typedef u16 u16x8 __attribute__((ext_vector_type(8)));

#define DEV static __device__ __forceinline__

static constexpr int ROWS = 8 * 2048;  // 16384
static constexpr int TAPS = 24;        // impulse-response taps (0.6^24 ~ 5e-6)
static constexpr int PADR = 64;        // pad rows per batch in dpad
static constexpr int DROWS = 2048 + PADR;

DEV u16 f2bf(float x) {
  u32 u = __float_as_uint(x);
  u += 0x7fffu + ((u >> 16) & 1u);
  return (u16)(u >> 16);
}

DEV void gld_lds16(const u16* g, u16* l) {
  __builtin_amdgcn_global_load_lds(
      (const __attribute__((address_space(1))) u32*)g,
      (__attribute__((address_space(3))) u32*)l, 16, 0, 0);
}

// ---------------- prep kernels ----------------

// Impulse response H[tau] of y[t]=M1 y[t-1]+M2 y[t-2], packed transposed bf16:
// Hp[l][o][tau*128 + j] = H_l[tau][o][j].
__global__ __launch_bounds__(128) void hprep_kernel(const float* __restrict__ my,
                                                    u16* __restrict__ Hp) {
  const int l = blockIdx.x >> 7, j = blockIdx.x & 127;
  const int o = threadIdx.x;
  const float* M = my + (size_t)l * 32768;  // [o][2][128]
  u32 mp1[64], mp2[64];
  {
    const float* r1 = M + (size_t)o * 256;
    const float* r2 = r1 + 128;
#pragma unroll
    for (int q = 0; q < 64; ++q) {
      mp1[q] = (u32)f2bf(r1[2 * q]) | ((u32)f2bf(r1[2 * q + 1]) << 16);
      mp2[q] = (u32)f2bf(r2[2 * q]) | ((u32)f2bf(r2[2 * q + 1]) << 16);
    }
  }
  __shared__ float vb[3][128];
  u16* HpL = Hp + ((size_t)l * 128 + o) * (TAPS * 128) + j;
  float v0 = (o == j) ? 1.f : 0.f;
  vb[0][o] = v0;
  vb[2][o] = 0.f;
  HpL[0] = f2bf(v0);
  __syncthreads();
  for (int tau = 1; tau < TAPS; ++tau) {
    const int a = (tau + 2) % 3;
    const int b = (tau + 1) % 3;
    const int c = tau % 3;
    const float* v1 = vb[a];
    const float* v2 = vb[b];
    float acc = 0.f;
#pragma unroll
    for (int q = 0; q < 64; ++q) {
      u32 w1 = mp1[q], w2 = mp2[q];
      float m1lo = __uint_as_float(w1 << 16);
      float m1hi = __uint_as_float(w1 & 0xffff0000u);
      float m2lo = __uint_as_float(w2 << 16);
      float m2hi = __uint_as_float(w2 & 0xffff0000u);
      acc += m1lo * v1[2 * q] + m1hi * v1[2 * q + 1];
      acc += m2lo * v2[2 * q] + m2hi * v2[2 * q + 1];
    }
    vb[c][o] = acc;
    HpL[tau * 128] = f2bf(acc);
    __syncthreads();
  }
}

// All other prep in one dispatch, partitioned by blockIdx.x:
// [0,64)       emb_w -> embT (transposed)
// [64,320)     w1 -> w1T
// [320,352)    proj_w -> projT
// [352,3808)   mphiT
// [3808,5856)  x f32 -> xbf bf16
// [5856,5888)  zero dpad pad rows
// [5888]       zero xtc shift-boundary slots
// [5889,6681)  Toeplitz tiles T[k][ti][64][64]
__global__ __launch_bounds__(256) void prep_misc(
    const float* __restrict__ emb_w, const float* __restrict__ w1,
    const float* __restrict__ proj_w, const float* __restrict__ mphi,
    const float* __restrict__ mu, const float* __restrict__ x,
    const float* __restrict__ evec, const float* __restrict__ evals,
    u16* __restrict__ embT, u16* __restrict__ w1T, u16* __restrict__ projT,
    u16* __restrict__ mphiT, u16* __restrict__ xbf, u16* __restrict__ dpad,
    u16* __restrict__ xtc, u16* __restrict__ Tbuf) {
  const int blk = blockIdx.x, tid = threadIdx.x;
  if (blk < 64) {
    int idx = blk * 256 + tid;
    int n = idx >> 7, k = idx & 127;
    embT[idx] = f2bf(emb_w[k * 128 + n]);
  } else if (blk < 320) {
    int l = (blk - 64) >> 7;
    int idx = ((blk - 64) & 127) * 256 + tid;  // < 32768
    int n = idx >> 7, k = idx & 127;
    w1T[l * 32768 + idx] = f2bf(w1[l * 32768 + k * 256 + n]);
  } else if (blk < 352) {
    int idx = (blk - 320) * 256 + tid;  // < 8192
    int n = idx >> 7, k = idx & 127;
    projT[idx] = f2bf(proj_w[k * 64 + n]);
  } else if (blk < 3808) {
    int l = (blk - 352) / 1728;
    int idx = ((blk - 352) % 1728) * 256 + tid;  // < 128*3456
    int o = idx / 3456, c = idx % 3456;
    float v;
    if (c < 3072) {
      v = mphi[(size_t)l * 3072 * 128 + (size_t)c * 128 + o];
    } else {
      int cc = c - 3072;
      int j = cc >> 7, i = cc & 127;
      v = mu[(size_t)l * 128 * 128 * 3 + ((size_t)o * 128 + i) * 3 + j];
    }
    mphiT[(size_t)l * 128 * 3456 + idx] = f2bf(v);
  } else if (blk < 5856) {
    int i = (blk - 3808) * 256 + tid;  // < 524288
    f32x4 v = *(const f32x4*)(x + (size_t)i * 4);
    u16x4 o;
    o[0] = f2bf(v[0]); o[1] = f2bf(v[1]); o[2] = f2bf(v[2]); o[3] = f2bf(v[3]);
    *(u16x4*)(xbf + (size_t)i * 4) = o;
  } else if (blk < 5888) {
    int i = (blk - 5856) * 256 + tid;  // < 8192
    int b = i >> 10, off = i & 1023;
    *(u16x8*)(dpad + (size_t)b * DROWS * 128 + off * 8) =
        (u16x8){0, 0, 0, 0, 0, 0, 0, 0};
  } else if (blk == 5888) {
    // xtc shift slots never written by ln_tr: (t=0, j=1,2) and (t=1, j=2)
    for (int e = tid; e < 3072; e += 256) {
      int b = e / 384, r = e % 384;
      size_t addr;
      if (r < 256) addr = ((size_t)b * 2048 + 0) * 3456 + 3200 + r;
      else addr = ((size_t)b * 2048 + 1) * 3456 + 3328 + (r - 256);
      xtc[addr] = 0;
    }
  } else {
    // Toeplitz tiles: T[k][ti][i][j] = ev_k^0.25 * phi_k[(ti-1)*64+i-j]
    int tb = blk - 5889;  // < 792
    int k = tb / 33, ti = tb % 33;
    float sc = powf(evals[k], 0.25f);
    u16* outp = Tbuf + (size_t)tb * 4096;
    for (int e = tid; e < 4096; e += 256) {
      int i = e >> 6, j = e & 63;
      int tau = (ti - 1) * 64 + i - j;
      float v = (tau >= 0 && tau < 2048) ? evec[tau * 24 + k] * sc : 0.f;
      outp[e] = f2bf(v);
    }
  }
}

// ---------------- elementwise / norm ----------------

// Fused LayerNorm + transpose + AR-shift scatter:
// h[f32] -> hlnT [b][d][t]  and  xtc shift cols (3072+j*128) at rows t+j.
__global__ __launch_bounds__(256) void ln_tr_kernel(
    const float* __restrict__ h, const float* __restrict__ gam,
    const float* __restrict__ bet, u16* __restrict__ hlnT,
    u16* __restrict__ xtc) {
  __shared__ u16 tile[64][136];
  const int b = blockIdx.x >> 5, st = blockIdx.x & 31;
  const int wrow = threadIdx.x >> 6;
  const int lane = threadIdx.x & 63;
  f32x2 g2 = *(const f32x2*)(gam + lane * 2);
  f32x2 b2 = *(const f32x2*)(bet + lane * 2);
#pragma unroll 4
  for (int it = 0; it < 16; ++it) {
    int lr = it * 4 + wrow;
    int t = st * 64 + lr;
    size_t row = (size_t)b * 2048 + t;
    f32x2 v = *(const f32x2*)(h + row * 128 + lane * 2);
    float s = v[0] + v[1];
#pragma unroll
    for (int o = 32; o; o >>= 1) s += __shfl_xor(s, o);
    float mu = s * (1.f / 128.f);
    float dx = v[0] - mu, dy = v[1] - mu;
    float q = dx * dx + dy * dy;
#pragma unroll
    for (int o = 32; o; o >>= 1) q += __shfl_xor(q, o);
    float rstd = rsqrtf(q * (1.f / 128.f) + 1e-5f);
    float o0 = dx * rstd * g2[0] + b2[0];
    float o1 = dy * rstd * g2[1] + b2[1];
    u32 pk = (u32)f2bf(o0) | ((u32)f2bf(o1) << 16);
    *(u32*)&tile[lr][lane * 2] = pk;
    *(u32*)&xtc[row * 3456 + 3072 + lane * 2] = pk;  // j=0
    if (t + 1 < 2048) *(u32*)&xtc[(row + 1) * 3456 + 3200 + lane * 2] = pk;
    if (t + 2 < 2048) *(u32*)&xtc[(row + 2) * 3456 + 3328 + lane * 2] = pk;
  }
  __syncthreads();
  const int d = threadIdx.x >> 1;
  const int half = threadIdx.x & 1;
#pragma unroll
  for (int i = 0; i < 4; ++i) {
    int sg = half * 4 + i;
    u16x8 w;
#pragma unroll
    for (int j = 0; j < 8; ++j) w[j] = tile[sg * 8 + j][d];
    *(u16x8*)(hlnT + ((size_t)b * 128 + d) * 2048 + st * 64 + sg * 8) = w;
  }
}

// ---------------- GEMMs ----------------
// LDS swizzle convention (both-sides): global source chunk c -> c ^ (row&7);
// fragment read chunk = (ks*4+hi) ^ (r&7). Linear LDS dest for global_load_lds.

// C[M,N](f32) = A[M,K](bf16,lda) @ BT[N,K](bf16,ldbt)^T + bias. (emb / proj)
template <int BM, int BN, int WROWS, int WCOLS>
__global__ __launch_bounds__(256) void gemm_bt(
    const u16* __restrict__ A, int lda, const u16* __restrict__ BT, int ldbt,
    float* __restrict__ C, int ldc, const float* __restrict__ bias, int kBlocks) {
  constexpr int WTM = BM / WROWS;
  constexpr int WTN = BN / WCOLS;
  constexpr int FM = WTM / 16;
  constexpr int FN = WTN / 16;
  static_assert(FM >= 1 && FN >= 1, "tile too small");
  __shared__ u16 As[BM * 64];
  __shared__ u16 Bs[BN * 64];
  const int tid = threadIdx.x;
  const int wid = tid >> 6, lane = tid & 63;
  const int bm = blockIdx.x, bn = blockIdx.y;
  const int wr = wid / WCOLS, wc = wid % WCOLS;
  const int r = lane & 15, hi = lane >> 4;

  f32x4 acc[FM][FN];
#pragma unroll
  for (int i = 0; i < FM; ++i)
#pragma unroll
    for (int j = 0; j < FN; ++j) acc[i][j] = (f32x4){0.f, 0.f, 0.f, 0.f};

  for (int kb = 0; kb < kBlocks; ++kb) {
    if (kb) __syncthreads();
#pragma unroll
    for (int it = 0; it < BM / 32; ++it) {
      int ci = it * 256 + tid;
      int sc = (ci & 7) ^ ((ci >> 3) & 7);
      gld_lds16(A + (size_t)(bm * BM + (ci >> 3)) * lda + kb * 64 + sc * 8,
                &As[(it * 256 + wid * 64) * 8]);
    }
#pragma unroll
    for (int it = 0; it < BN / 32; ++it) {
      int ci = it * 256 + tid;
      int sc = (ci & 7) ^ ((ci >> 3) & 7);
      gld_lds16(BT + (size_t)(bn * BN + (ci >> 3)) * ldbt + kb * 64 + sc * 8,
                &Bs[(it * 256 + wid * 64) * 8]);
    }
    __syncthreads();
#pragma unroll
    for (int ks = 0; ks < 2; ++ks) {
      const int sk = ((ks * 4 + hi) ^ (r & 7)) << 3;
      bf16x8 af[FM], bfv[FN];
#pragma unroll
      for (int fm = 0; fm < FM; ++fm)
        af[fm] = *(const bf16x8*)&As[(wr * WTM + fm * 16 + r) * 64 + sk];
#pragma unroll
      for (int fn = 0; fn < FN; ++fn)
        bfv[fn] = *(const bf16x8*)&Bs[(wc * WTN + fn * 16 + r) * 64 + sk];
#pragma unroll
      for (int fm = 0; fm < FM; ++fm)
#pragma unroll
        for (int fn = 0; fn < FN; ++fn)
          acc[fm][fn] = __builtin_amdgcn_mfma_f32_16x16x32_bf16(
              af[fm], bfv[fn], acc[fm][fn], 0, 0, 0);
    }
  }
#pragma unroll
  for (int fm = 0; fm < FM; ++fm) {
#pragma unroll
    for (int fn = 0; fn < FN; ++fn) {
      const int col = bn * BN + wc * WTN + fn * 16 + r;
      const float bv = bias ? bias[col] : 0.f;
#pragma unroll
      for (int q = 0; q < 4; ++q) {
        const int row = bm * BM + wr * WTM + fm * 16 + hi * 4 + q;
        C[(size_t)row * ldc + col] = acc[fm][fn][q] + bv;
      }
    }
  }
}

// delta = xtc @ mphiT^T -> bf16 dpad.  BM=32, BN=128, K=54*64.
// 512 threads / 8 waves (2 M-rows x 4 N-cols) for 16 waves/CU latency hiding.
// Double-buffered issue-early prefetch.
__global__ __launch_bounds__(512) void gemm_delta(
    const u16* __restrict__ A, const u16* __restrict__ BT,
    u16* __restrict__ dpad) {
  __shared__ u16 As[2][32 * 64];
  __shared__ u16 Bs[2][128 * 64];
  const int tid = threadIdx.x;  // 0..511
  const int wid = tid >> 6, lane = tid & 63;
  const int bm = blockIdx.x;
  const int wr = wid >> 2, wc = wid & 3;  // WTM=16, WTN=32 -> FM=1, FN=2
  const int r = lane & 15, hi = lane >> 4;

  f32x4 acc[2];
#pragma unroll
  for (int j = 0; j < 2; ++j) acc[j] = (f32x4){0.f, 0.f, 0.f, 0.f};

  auto stage = [&](int kb, int p) {
    if (tid < 256) {  // waves 0-3 stage A (32x64 = 4KB)
      int ci = tid;
      int sc = (ci & 7) ^ ((ci >> 3) & 7);
      gld_lds16(A + (size_t)(bm * 32 + (ci >> 3)) * 3456 + kb * 64 + sc * 8,
                &As[p][(wid * 64) * 8]);
    }
#pragma unroll
    for (int it = 0; it < 2; ++it) {  // B: 128x64 = 16KB
      int ci = it * 512 + tid;
      int sc = (ci & 7) ^ ((ci >> 3) & 7);
      gld_lds16(BT + (size_t)(ci >> 3) * 3456 + kb * 64 + sc * 8,
                &Bs[p][(it * 512 + wid * 64) * 8]);
    }
  };

  stage(0, 0);
  __syncthreads();
  for (int kb = 0; kb < 54; ++kb) {
    const int p = kb & 1;
    if (kb < 53) stage(kb + 1, p ^ 1);  // issue next-tile loads (async)
#pragma unroll
    for (int ks = 0; ks < 2; ++ks) {
      const int sk = ((ks * 4 + hi) ^ (r & 7)) << 3;
      bf16x8 af = *(const bf16x8*)&As[p][(wr * 16 + r) * 64 + sk];
      bf16x8 bfv[2];
#pragma unroll
      for (int fn = 0; fn < 2; ++fn)
        bfv[fn] = *(const bf16x8*)&Bs[p][(wc * 32 + fn * 16 + r) * 64 + sk];
#pragma unroll
      for (int fn = 0; fn < 2; ++fn)
        acc[fn] = __builtin_amdgcn_mfma_f32_16x16x32_bf16(af, bfv[fn], acc[fn], 0, 0, 0);
    }
    __syncthreads();  // drains prefetch; next buffer ready
  }
#pragma unroll
  for (int fn = 0; fn < 2; ++fn) {
    const int col = wc * 32 + fn * 16 + r;
#pragma unroll
    for (int q = 0; q < 4; ++q) {
      const int row = bm * 32 + wr * 16 + hi * 4 + q;
      int bb = row >> 11, t = row & 2047;
      dpad[((size_t)(bb * DROWS + PADR + t)) * 128 + col] = f2bf(acc[fn][q]);
    }
  }
}

// Spectral conv as block-Toeplitz GEMM, FILTER-PAIR per block: the B (hlnT)
// tile is staged ONCE and shared by two filters' A-rings -> staged bytes per
// MFMA drop 33% (24KB/128 -> 32KB/256). Same 128-row tile, 2-slot rings,
// 256 threads, longest-first skew, XCD partition (3 kc-pairs x 4 b per XCD).
// xtc[b][t][kc*128 + d] (ld 3456)
__global__ __launch_bounds__(256, 3) void gemm_conv(
    const u16* __restrict__ T, const u16* __restrict__ hlnT,
    u16* __restrict__ xtc) {
  __shared__ u16 As[2][2][64 * 64];  // [filter][ring slot]
  __shared__ u16 Bs[128 * 64];
  const int tid = threadIdx.x;
  const int wid = tid >> 6, lane = tid & 63;
  // bid -> (tt, kcp, b): xcd = bid&7 owns kcp in [(xcd>>1)*3, +3) and
  // b in [(xcd&1)*4, +4). slot = bid>>3 orders tt longest-first.
  const int xcd = blockIdx.x & 7;
  const int slot = blockIdx.x >> 3;        // 0..191
  const int tt = slot / 12;                // 0 => longest (t0 = 1920)
  const int rem12 = slot % 12;
  const int kcp = (xcd >> 1) * 3 + rem12 % 3;  // 0..11
  const int b = (xcd & 1) * 4 + rem12 / 3;
  const int kc0 = kcp * 2;
  const int t0 = (15 - tt) << 7;
  const int r = lane & 15, hi = lane >> 4;
  const int wr = wid >> 1, wc = wid & 1;

  f32x4 acc[2][4][4];
#pragma unroll
  for (int f = 0; f < 2; ++f)
#pragma unroll
    for (int i = 0; i < 4; ++i)
#pragma unroll
      for (int j = 0; j < 4; ++j) acc[f][i][j] = (f32x4){0.f, 0.f, 0.f, 0.f};

  const u16* Tk0 = T + (size_t)kc0 * 33 * 4096;
  const u16* Tk1 = Tk0 + 33 * 4096;
  const u16* Bb = hlnT + (size_t)b * 128 * 2048;
  const int base = t0 >> 6;
  const int nsb = base + 2;

  // stage one 8KB A tile (ti) of filter f into ring slot p (2 x 256-thread iters)
  auto stageA = [&](const u16* Tk, int f, int ti, int p) {
#pragma unroll
    for (int it = 0; it < 2; ++it) {
      int ci = it * 256 + tid;
      int sc = (ci & 7) ^ ((ci >> 3) & 7);
      gld_lds16(Tk + (size_t)ti * 4096 + (ci >> 3) * 64 + sc * 8,
                &As[f][p][(it * 256 + wid * 64) * 8]);
    }
  };

  for (int sb = 0; sb < nsb; ++sb) {
    const int dlt = base - sb;
    const int p = sb & 1;
    if (sb) __syncthreads();
    stageA(Tk0, 0, dlt + 1, p);
    stageA(Tk1, 1, dlt + 1, p);
    if (sb == 0) {
      stageA(Tk0, 0, dlt + 2, 1);
      stageA(Tk1, 1, dlt + 2, 1);
    }
#pragma unroll
    for (int it = 0; it < 4; ++it) {
      int ci = it * 256 + tid;
      int sc = (ci & 7) ^ ((ci >> 3) & 7);
      gld_lds16(Bb + (size_t)(ci >> 3) * 2048 + sb * 64 + sc * 8,
                &Bs[(it * 256 + wid * 64) * 8]);
    }
    __syncthreads();
#pragma unroll
    for (int ks = 0; ks < 2; ++ks) {
      const int sk = ((ks * 4 + hi) ^ (r & 7)) << 3;
      bf16x8 bfv[4];
#pragma unroll
      for (int fn = 0; fn < 4; ++fn)
        bfv[fn] = *(const bf16x8*)&Bs[(wc * 64 + fn * 16 + r) * 64 + sk];
#pragma unroll
      for (int f = 0; f < 2; ++f) {
        // wave-row wr=0 reads tile dlt+1 (slot p); wr=1 reads dlt+2 (slot p^1)
        const u16* Aw = As[f][p ^ wr];
        bf16x8 af[4];
#pragma unroll
        for (int fm = 0; fm < 4; ++fm)
          af[fm] = *(const bf16x8*)&Aw[(fm * 16 + r) * 64 + sk];
#pragma unroll
        for (int fm = 0; fm < 4; ++fm)
#pragma unroll
          for (int fn = 0; fn < 4; ++fn)
            acc[f][fm][fn] = __builtin_amdgcn_mfma_f32_16x16x32_bf16(
                af[fm], bfv[fn], acc[f][fm][fn], 0, 0, 0);
      }
    }
  }
#pragma unroll
  for (int f = 0; f < 2; ++f)
#pragma unroll
    for (int fm = 0; fm < 4; ++fm) {
#pragma unroll
      for (int fn = 0; fn < 4; ++fn) {
        const int col = wc * 64 + fn * 16 + r;
#pragma unroll
        for (int q = 0; q < 4; ++q) {
          const int row = t0 + wr * 64 + fm * 16 + hi * 4 + q;
          xtc[((size_t)(b * 2048 + row)) * 3456 + (kc0 + f) * 128 + col] =
              f2bf(acc[f][fm][fn][q]);
        }
      }
    }
}

// y-conv: y[t] = sum_tau H[tau] delta[t-tau]; banded block-Toeplitz over dpad.
// BK=128 (one full tap per stage). Epilogue: ybf = bf16(gelu(y)).
__global__ __launch_bounds__(256) void gemm_yconv(
    const u16* __restrict__ dpad, const u16* __restrict__ Hp,
    u16* __restrict__ ybf) {
  __shared__ u16 As[64 * 128];
  __shared__ u16 Bs[64 * 128];
  const int tid = threadIdx.x;
  const int wid = tid >> 6, lane = tid & 63;
  const int bm = blockIdx.x, bn = blockIdx.y;
  const int b = bm >> 5, t0 = (bm & 31) << 6;
  const int r = lane & 15, hi = lane >> 4;

  f32x4 acc[4];
#pragma unroll
  for (int j = 0; j < 4; ++j) acc[j] = (f32x4){0.f, 0.f, 0.f, 0.f};

  const u16* Ab = dpad + (size_t)b * DROWS * 128;
  for (int tap = 0; tap < TAPS; ++tap) {
    const u16* Ap = Ab + (size_t)(PADR + t0 - tap) * 128;
    if (tap) __syncthreads();
#pragma unroll
    for (int it = 0; it < 4; ++it) {
      int ci = it * 256 + tid;
      int row = ci >> 4;
      int sc = (ci & 15) ^ (row & 7);
      gld_lds16(Ap + (size_t)row * 128 + sc * 8,
                &As[(it * 256 + wid * 64) * 8]);
    }
#pragma unroll
    for (int it = 0; it < 4; ++it) {
      int ci = it * 256 + tid;
      int row = ci >> 4;
      int sc = (ci & 15) ^ (row & 7);
      gld_lds16(Hp + (size_t)(bn * 64 + row) * (TAPS * 128) + tap * 128 + sc * 8,
                &Bs[(it * 256 + wid * 64) * 8]);
    }
    __syncthreads();
#pragma unroll
    for (int ks = 0; ks < 4; ++ks) {
      const int sk = ((ks * 4 + hi) ^ (r & 7)) << 3;
      bf16x8 af = *(const bf16x8*)&As[(wid * 16 + r) * 128 + sk];
      bf16x8 bfv[4];
#pragma unroll
      for (int fn = 0; fn < 4; ++fn)
        bfv[fn] = *(const bf16x8*)&Bs[(fn * 16 + r) * 128 + sk];
#pragma unroll
      for (int fn = 0; fn < 4; ++fn)
        acc[fn] = __builtin_amdgcn_mfma_f32_16x16x32_bf16(af, bfv[fn], acc[fn], 0, 0, 0);
    }
  }
#pragma unroll
  for (int fn = 0; fn < 4; ++fn) {
    const int col = bn * 64 + fn * 16 + r;
#pragma unroll
    for (int q = 0; q < 4; ++q) {
      const int row = t0 + wid * 16 + hi * 4 + q;
      float v = acc[fn][q];
      float gl = 0.5f * v * (1.f + erff(v * 0.70710678118654752f));
      ybf[((size_t)(b * 2048 + row)) * 128 + col] = f2bf(gl);
    }
  }
}

// w1 GEMM (BM=32, BN=256, grid 512) with fused GLU + residual epilogue.
__global__ __launch_bounds__(256) void gemm_w1glu(
    const u16* __restrict__ ybf, const u16* __restrict__ w1T,
    const float* __restrict__ b1, float* __restrict__ h,
    u16* __restrict__ hbf) {
  __shared__ u16 As[32 * 64];
  __shared__ u16 Bs[256 * 64];
  __shared__ float sg[32][128];
  const int tid = threadIdx.x;
  const int wid = tid >> 6, lane = tid & 63;
  const int bm = blockIdx.x;
  const int wr = wid >> 1, wc = wid & 1;  // WTM=16, WTN=128
  const int r = lane & 15, hi = lane >> 4;

  f32x4 acc[8];
#pragma unroll
  for (int j = 0; j < 8; ++j) acc[j] = (f32x4){0.f, 0.f, 0.f, 0.f};

  for (int kb = 0; kb < 2; ++kb) {
    if (kb) __syncthreads();
    {
      int ci = tid;
      int sc = (ci & 7) ^ ((ci >> 3) & 7);
      gld_lds16(ybf + (size_t)(bm * 32 + (ci >> 3)) * 128 + kb * 64 + sc * 8,
                &As[(wid * 64) * 8]);
    }
#pragma unroll
    for (int it = 0; it < 8; ++it) {
      int ci = it * 256 + tid;
      int sc = (ci & 7) ^ ((ci >> 3) & 7);
      gld_lds16(w1T + (size_t)(ci >> 3) * 128 + kb * 64 + sc * 8,
                &Bs[(it * 256 + wid * 64) * 8]);
    }
    __syncthreads();
#pragma unroll
    for (int ks = 0; ks < 2; ++ks) {
      const int sk = ((ks * 4 + hi) ^ (r & 7)) << 3;
      bf16x8 af = *(const bf16x8*)&As[(wr * 16 + r) * 64 + sk];
      bf16x8 bfv[8];
#pragma unroll
      for (int fn = 0; fn < 8; ++fn)
        bfv[fn] = *(const bf16x8*)&Bs[(wc * 128 + fn * 16 + r) * 64 + sk];
#pragma unroll
      for (int fn = 0; fn < 8; ++fn)
        acc[fn] = __builtin_amdgcn_mfma_f32_16x16x32_bf16(af, bfv[fn], acc[fn], 0, 0, 0);
    }
  }
  __syncthreads();
  if (wc == 1) {
#pragma unroll
    for (int fn = 0; fn < 8; ++fn) {
      const int colg = fn * 16 + r;
      const float bv = b1[128 + colg];
#pragma unroll
      for (int q = 0; q < 4; ++q) {
        const int rl = wr * 16 + hi * 4 + q;
        float v = acc[fn][q] + bv;
        sg[rl][colg] = 1.f / (1.f + expf(-v));
      }
    }
  }
  __syncthreads();
  if (wc == 0) {
#pragma unroll
    for (int fn = 0; fn < 8; ++fn) {
      const int col = fn * 16 + r;
      const float bv = b1[col];
#pragma unroll
      for (int q = 0; q < 4; ++q) {
        const int rl = wr * 16 + hi * 4 + q;
        const size_t row = (size_t)bm * 32 + rl;
        float a = acc[fn][q] + bv;
        float hn = a * sg[rl][col] + h[row * 128 + col];
        h[row * 128 + col] = hn;
        hbf[row * 128 + col] = f2bf(hn);
      }
    }
  }
}

// ---------------- host ----------------

extern "C" void kernel_launch(void* const* d_in, const int* in_sizes, int n_in,
                              void* d_out, int out_size, void* d_ws, size_t ws_size,
                              hipStream_t stream) {
  (void)in_sizes; (void)n_in; (void)out_size; (void)ws_size;
  const float* x = (const float*)d_in[0];
  const float* emb_w = (const float*)d_in[1];
  const float* emb_b = (const float*)d_in[2];
  const float* ln_g = (const float*)d_in[3];
  const float* ln_b = (const float*)d_in[4];
  const float* m_phi = (const float*)d_in[5];
  const float* m_u = (const float*)d_in[6];
  const float* m_y = (const float*)d_in[7];
  const float* w1 = (const float*)d_in[8];
  const float* b1 = (const float*)d_in[9];
  const float* proj_w = (const float*)d_in[10];
  const float* proj_b = (const float*)d_in[11];
  const float* evals = (const float*)d_in[12];
  const float* evec = (const float*)d_in[13];
  float* out = (float*)d_out;

  char* p = (char*)d_ws;
  auto carve = [&](size_t bytes) {
    char* r = p;
    p += (bytes + 255) & ~(size_t)255;
    return r;
  };
  u16* Tbuf = (u16*)carve((size_t)24 * 33 * 4096 * 2);
  u16* embT = (u16*)carve(128 * 128 * 2);
  u16* w1T = (u16*)carve((size_t)2 * 256 * 128 * 2);
  u16* projT = (u16*)carve(64 * 128 * 2);
  u16* mphiT = (u16*)carve((size_t)2 * 128 * 3456 * 2);
  u16* Hp = (u16*)carve((size_t)2 * 128 * TAPS * 128 * 2);
  u16* xbf = (u16*)carve((size_t)ROWS * 128 * 2);
  float* h = (float*)carve((size_t)ROWS * 128 * 4);
  u16* hbf = (u16*)carve((size_t)ROWS * 128 * 2);
  u16* hlnT = (u16*)carve((size_t)ROWS * 128 * 2);
  u16* xtc = (u16*)carve((size_t)ROWS * 3456 * 2);
  u16* dpad = (u16*)carve((size_t)8 * DROWS * 128 * 2);
  u16* ybf = (u16*)carve((size_t)ROWS * 128 * 2);

  hprep_kernel<<<dim3(256), dim3(128), 0, stream>>>(m_y, Hp);
  prep_misc<<<dim3(6681), dim3(256), 0, stream>>>(
      emb_w, w1, proj_w, m_phi, m_u, x, evec, evals,
      embT, w1T, projT, mphiT, xbf, dpad, xtc, Tbuf);

  // h = x @ emb_w + emb_b
  gemm_bt<32, 128, 2, 2><<<dim3(512, 1), dim3(256), 0, stream>>>(
      xbf, 128, embT, 128, h, 128, emb_b, 2);

  for (int l = 0; l < 2; ++l) {
    const u16* mT = mphiT + (size_t)l * 128 * 3456;
    ln_tr_kernel<<<dim3(256), dim3(256), 0, stream>>>(
        h, ln_g + l * 128, ln_b + l * 128, hlnT, xtc);
    gemm_conv<<<dim3(1536), dim3(256), 0, stream>>>(Tbuf, hlnT, xtc);
    gemm_delta<<<dim3(512), dim3(512), 0, stream>>>(xtc, mT, dpad);
    gemm_yconv<<<dim3(256, 2), dim3(256), 0, stream>>>(
        dpad, Hp + (size_t)l * 128 * TAPS * 128, ybf);
    gemm_w1glu<<<dim3(512), dim3(256), 0, stream>>>(
        ybf, w1T + (size_t)l * 256 * 128, b1 + l * 256, h, hbf);
  }

  // out = h @ proj_w + proj_b
  gemm_bt<32, 64, 2, 2><<<dim3(512, 1), dim3(256), 0, stream>>>(
      hbf, 128, projT, 128, out, 64, proj_b, 2);
}

// Round 14
// 461.263 us; speedup vs baseline: 1.1422x; 1.1422x over previous
//
#include <hip/hip_runtime.h>

typedef unsigned short u16;
typedef unsigned int u32;
typedef __bf16 bf16x8 __attribute__((ext_vector_type(8)));
typedef float f32x4 __attribute__((ext_vector_type(4)));
typedef float f32x2 __attribute__((ext_vector_type(2)));
typedef u16 u16x4 __attribute__((ext_vector_type(4)));
typedef u16 u16x8 __attribute__((ext_vector_type(8)));

#define DEV static __device__ __forceinline__

static constexpr int ROWS = 8 * 2048;  // 16384
static constexpr int TAPS = 24;        // impulse-response taps (0.6^24 ~ 5e-6)
static constexpr int PADR = 64;        // pad rows per batch in dpad
static constexpr int DROWS = 2048 + PADR;

DEV u16 f2bf(float x) {
  u32 u = __float_as_uint(x);
  u += 0x7fffu + ((u >> 16) & 1u);
  return (u16)(u >> 16);
}

DEV void gld_lds16(const u16* g, u16* l) {
  __builtin_amdgcn_global_load_lds(
      (const __attribute__((address_space(1))) u32*)g,
      (__attribute__((address_space(3))) u32*)l, 16, 0, 0);
}

// ---------------- prep kernels ----------------

// Impulse response H[tau] of y[t]=M1 y[t-1]+M2 y[t-2], packed transposed bf16:
// Hp[l][o][tau*128 + j] = H_l[tau][o][j].
__global__ __launch_bounds__(128) void hprep_kernel(const float* __restrict__ my,
                                                    u16* __restrict__ Hp) {
  const int l = blockIdx.x >> 7, j = blockIdx.x & 127;
  const int o = threadIdx.x;
  const float* M = my + (size_t)l * 32768;  // [o][2][128]
  u32 mp1[64], mp2[64];
  {
    const float* r1 = M + (size_t)o * 256;
    const float* r2 = r1 + 128;
#pragma unroll
    for (int q = 0; q < 64; ++q) {
      mp1[q] = (u32)f2bf(r1[2 * q]) | ((u32)f2bf(r1[2 * q + 1]) << 16);
      mp2[q] = (u32)f2bf(r2[2 * q]) | ((u32)f2bf(r2[2 * q + 1]) << 16);
    }
  }
  __shared__ float vb[3][128];
  u16* HpL = Hp + ((size_t)l * 128 + o) * (TAPS * 128) + j;
  float v0 = (o == j) ? 1.f : 0.f;
  vb[0][o] = v0;
  vb[2][o] = 0.f;
  HpL[0] = f2bf(v0);
  __syncthreads();
  for (int tau = 1; tau < TAPS; ++tau) {
    const int a = (tau + 2) % 3;
    const int b = (tau + 1) % 3;
    const int c = tau % 3;
    const float* v1 = vb[a];
    const float* v2 = vb[b];
    float acc = 0.f;
#pragma unroll
    for (int q = 0; q < 64; ++q) {
      u32 w1 = mp1[q], w2 = mp2[q];
      float m1lo = __uint_as_float(w1 << 16);
      float m1hi = __uint_as_float(w1 & 0xffff0000u);
      float m2lo = __uint_as_float(w2 << 16);
      float m2hi = __uint_as_float(w2 & 0xffff0000u);
      acc += m1lo * v1[2 * q] + m1hi * v1[2 * q + 1];
      acc += m2lo * v2[2 * q] + m2hi * v2[2 * q + 1];
    }
    vb[c][o] = acc;
    HpL[tau * 128] = f2bf(acc);
    __syncthreads();
  }
}

// All other prep in one dispatch, partitioned by blockIdx.x:
// [0,64)       emb_w -> embT (transposed)
// [64,320)     w1 -> w1T
// [320,352)    proj_w -> projT
// [352,3808)   mphiT
// [3808,5856)  x f32 -> xbf bf16
// [5856,5888)  zero dpad pad rows
// [5888]       zero xtc shift-boundary slots
// [5889,6681)  Toeplitz tiles T[k][ti][64][64]
__global__ __launch_bounds__(256) void prep_misc(
    const float* __restrict__ emb_w, const float* __restrict__ w1,
    const float* __restrict__ proj_w, const float* __restrict__ mphi,
    const float* __restrict__ mu, const float* __restrict__ x,
    const float* __restrict__ evec, const float* __restrict__ evals,
    u16* __restrict__ embT, u16* __restrict__ w1T, u16* __restrict__ projT,
    u16* __restrict__ mphiT, u16* __restrict__ xbf, u16* __restrict__ dpad,
    u16* __restrict__ xtc, u16* __restrict__ Tbuf) {
  const int blk = blockIdx.x, tid = threadIdx.x;
  if (blk < 64) {
    int idx = blk * 256 + tid;
    int n = idx >> 7, k = idx & 127;
    embT[idx] = f2bf(emb_w[k * 128 + n]);
  } else if (blk < 320) {
    int l = (blk - 64) >> 7;
    int idx = ((blk - 64) & 127) * 256 + tid;  // < 32768
    int n = idx >> 7, k = idx & 127;
    w1T[l * 32768 + idx] = f2bf(w1[l * 32768 + k * 256 + n]);
  } else if (blk < 352) {
    int idx = (blk - 320) * 256 + tid;  // < 8192
    int n = idx >> 7, k = idx & 127;
    projT[idx] = f2bf(proj_w[k * 64 + n]);
  } else if (blk < 3808) {
    int l = (blk - 352) / 1728;
    int idx = ((blk - 352) % 1728) * 256 + tid;  // < 128*3456
    int o = idx / 3456, c = idx % 3456;
    float v;
    if (c < 3072) {
      v = mphi[(size_t)l * 3072 * 128 + (size_t)c * 128 + o];
    } else {
      int cc = c - 3072;
      int j = cc >> 7, i = cc & 127;
      v = mu[(size_t)l * 128 * 128 * 3 + ((size_t)o * 128 + i) * 3 + j];
    }
    mphiT[(size_t)l * 128 * 3456 + idx] = f2bf(v);
  } else if (blk < 5856) {
    int i = (blk - 3808) * 256 + tid;  // < 524288
    f32x4 v = *(const f32x4*)(x + (size_t)i * 4);
    u16x4 o;
    o[0] = f2bf(v[0]); o[1] = f2bf(v[1]); o[2] = f2bf(v[2]); o[3] = f2bf(v[3]);
    *(u16x4*)(xbf + (size_t)i * 4) = o;
  } else if (blk < 5888) {
    int i = (blk - 5856) * 256 + tid;  // < 8192
    int b = i >> 10, off = i & 1023;
    *(u16x8*)(dpad + (size_t)b * DROWS * 128 + off * 8) =
        (u16x8){0, 0, 0, 0, 0, 0, 0, 0};
  } else if (blk == 5888) {
    // xtc shift slots never written by ln_tr: (t=0, j=1,2) and (t=1, j=2)
    for (int e = tid; e < 3072; e += 256) {
      int b = e / 384, r = e % 384;
      size_t addr;
      if (r < 256) addr = ((size_t)b * 2048 + 0) * 3456 + 3200 + r;
      else addr = ((size_t)b * 2048 + 1) * 3456 + 3328 + (r - 256);
      xtc[addr] = 0;
    }
  } else {
    // Toeplitz tiles: T[k][ti][i][j] = ev_k^0.25 * phi_k[(ti-1)*64+i-j]
    int tb = blk - 5889;  // < 792
    int k = tb / 33, ti = tb % 33;
    float sc = powf(evals[k], 0.25f);
    u16* outp = Tbuf + (size_t)tb * 4096;
    for (int e = tid; e < 4096; e += 256) {
      int i = e >> 6, j = e & 63;
      int tau = (ti - 1) * 64 + i - j;
      float v = (tau >= 0 && tau < 2048) ? evec[tau * 24 + k] * sc : 0.f;
      outp[e] = f2bf(v);
    }
  }
}

// ---------------- elementwise / norm ----------------

// Fused LayerNorm + transpose + AR-shift scatter:
// h[f32] -> hlnT [b][d][t]  and  xtc shift cols (3072+j*128) at rows t+j.
__global__ __launch_bounds__(256) void ln_tr_kernel(
    const float* __restrict__ h, const float* __restrict__ gam,
    const float* __restrict__ bet, u16* __restrict__ hlnT,
    u16* __restrict__ xtc) {
  __shared__ u16 tile[64][136];
  const int b = blockIdx.x >> 5, st = blockIdx.x & 31;
  const int wrow = threadIdx.x >> 6;
  const int lane = threadIdx.x & 63;
  f32x2 g2 = *(const f32x2*)(gam + lane * 2);
  f32x2 b2 = *(const f32x2*)(bet + lane * 2);
#pragma unroll 4
  for (int it = 0; it < 16; ++it) {
    int lr = it * 4 + wrow;
    int t = st * 64 + lr;
    size_t row = (size_t)b * 2048 + t;
    f32x2 v = *(const f32x2*)(h + row * 128 + lane * 2);
    float s = v[0] + v[1];
#pragma unroll
    for (int o = 32; o; o >>= 1) s += __shfl_xor(s, o);
    float mu = s * (1.f / 128.f);
    float dx = v[0] - mu, dy = v[1] - mu;
    float q = dx * dx + dy * dy;
#pragma unroll
    for (int o = 32; o; o >>= 1) q += __shfl_xor(q, o);
    float rstd = rsqrtf(q * (1.f / 128.f) + 1e-5f);
    float o0 = dx * rstd * g2[0] + b2[0];
    float o1 = dy * rstd * g2[1] + b2[1];
    u32 pk = (u32)f2bf(o0) | ((u32)f2bf(o1) << 16);
    *(u32*)&tile[lr][lane * 2] = pk;
    *(u32*)&xtc[row * 3456 + 3072 + lane * 2] = pk;  // j=0
    if (t + 1 < 2048) *(u32*)&xtc[(row + 1) * 3456 + 3200 + lane * 2] = pk;
    if (t + 2 < 2048) *(u32*)&xtc[(row + 2) * 3456 + 3328 + lane * 2] = pk;
  }
  __syncthreads();
  const int d = threadIdx.x >> 1;
  const int half = threadIdx.x & 1;
#pragma unroll
  for (int i = 0; i < 4; ++i) {
    int sg = half * 4 + i;
    u16x8 w;
#pragma unroll
    for (int j = 0; j < 8; ++j) w[j] = tile[sg * 8 + j][d];
    *(u16x8*)(hlnT + ((size_t)b * 128 + d) * 2048 + st * 64 + sg * 8) = w;
  }
}

// ---------------- GEMMs ----------------
// LDS swizzle convention (both-sides): global source chunk c -> c ^ (row&7);
// fragment read chunk = (ks*4+hi) ^ (r&7). Linear LDS dest for global_load_lds.

// C[M,N](f32) = A[M,K](bf16,lda) @ BT[N,K](bf16,ldbt)^T + bias. (emb / proj)
template <int BM, int BN, int WROWS, int WCOLS>
__global__ __launch_bounds__(256) void gemm_bt(
    const u16* __restrict__ A, int lda, const u16* __restrict__ BT, int ldbt,
    float* __restrict__ C, int ldc, const float* __restrict__ bias, int kBlocks) {
  constexpr int WTM = BM / WROWS;
  constexpr int WTN = BN / WCOLS;
  constexpr int FM = WTM / 16;
  constexpr int FN = WTN / 16;
  static_assert(FM >= 1 && FN >= 1, "tile too small");
  __shared__ u16 As[BM * 64];
  __shared__ u16 Bs[BN * 64];
  const int tid = threadIdx.x;
  const int wid = tid >> 6, lane = tid & 63;
  const int bm = blockIdx.x, bn = blockIdx.y;
  const int wr = wid / WCOLS, wc = wid % WCOLS;
  const int r = lane & 15, hi = lane >> 4;

  f32x4 acc[FM][FN];
#pragma unroll
  for (int i = 0; i < FM; ++i)
#pragma unroll
    for (int j = 0; j < FN; ++j) acc[i][j] = (f32x4){0.f, 0.f, 0.f, 0.f};

  for (int kb = 0; kb < kBlocks; ++kb) {
    if (kb) __syncthreads();
#pragma unroll
    for (int it = 0; it < BM / 32; ++it) {
      int ci = it * 256 + tid;
      int sc = (ci & 7) ^ ((ci >> 3) & 7);
      gld_lds16(A + (size_t)(bm * BM + (ci >> 3)) * lda + kb * 64 + sc * 8,
                &As[(it * 256 + wid * 64) * 8]);
    }
#pragma unroll
    for (int it = 0; it < BN / 32; ++it) {
      int ci = it * 256 + tid;
      int sc = (ci & 7) ^ ((ci >> 3) & 7);
      gld_lds16(BT + (size_t)(bn * BN + (ci >> 3)) * ldbt + kb * 64 + sc * 8,
                &Bs[(it * 256 + wid * 64) * 8]);
    }
    __syncthreads();
#pragma unroll
    for (int ks = 0; ks < 2; ++ks) {
      const int sk = ((ks * 4 + hi) ^ (r & 7)) << 3;
      bf16x8 af[FM], bfv[FN];
#pragma unroll
      for (int fm = 0; fm < FM; ++fm)
        af[fm] = *(const bf16x8*)&As[(wr * WTM + fm * 16 + r) * 64 + sk];
#pragma unroll
      for (int fn = 0; fn < FN; ++fn)
        bfv[fn] = *(const bf16x8*)&Bs[(wc * WTN + fn * 16 + r) * 64 + sk];
#pragma unroll
      for (int fm = 0; fm < FM; ++fm)
#pragma unroll
        for (int fn = 0; fn < FN; ++fn)
          acc[fm][fn] = __builtin_amdgcn_mfma_f32_16x16x32_bf16(
              af[fm], bfv[fn], acc[fm][fn], 0, 0, 0);
    }
  }
#pragma unroll
  for (int fm = 0; fm < FM; ++fm) {
#pragma unroll
    for (int fn = 0; fn < FN; ++fn) {
      const int col = bn * BN + wc * WTN + fn * 16 + r;
      const float bv = bias ? bias[col] : 0.f;
#pragma unroll
      for (int q = 0; q < 4; ++q) {
        const int row = bm * BM + wr * WTM + fm * 16 + hi * 4 + q;
        C[(size_t)row * ldc + col] = acc[fm][fn][q] + bv;
      }
    }
  }
}

// delta = xtc @ mphiT^T -> bf16 dpad.  BM=32, BN=128, K=54*64.
// 512 threads / 8 waves (2 M-rows x 4 N-cols) for 16 waves/CU latency hiding.
// Double-buffered issue-early prefetch.
__global__ __launch_bounds__(512) void gemm_delta(
    const u16* __restrict__ A, const u16* __restrict__ BT,
    u16* __restrict__ dpad) {
  __shared__ u16 As[2][32 * 64];
  __shared__ u16 Bs[2][128 * 64];
  const int tid = threadIdx.x;  // 0..511
  const int wid = tid >> 6, lane = tid & 63;
  const int bm = blockIdx.x;
  const int wr = wid >> 2, wc = wid & 3;  // WTM=16, WTN=32 -> FM=1, FN=2
  const int r = lane & 15, hi = lane >> 4;

  f32x4 acc[2];
#pragma unroll
  for (int j = 0; j < 2; ++j) acc[j] = (f32x4){0.f, 0.f, 0.f, 0.f};

  auto stage = [&](int kb, int p) {
    if (tid < 256) {  // waves 0-3 stage A (32x64 = 4KB)
      int ci = tid;
      int sc = (ci & 7) ^ ((ci >> 3) & 7);
      gld_lds16(A + (size_t)(bm * 32 + (ci >> 3)) * 3456 + kb * 64 + sc * 8,
                &As[p][(wid * 64) * 8]);
    }
#pragma unroll
    for (int it = 0; it < 2; ++it) {  // B: 128x64 = 16KB
      int ci = it * 512 + tid;
      int sc = (ci & 7) ^ ((ci >> 3) & 7);
      gld_lds16(BT + (size_t)(ci >> 3) * 3456 + kb * 64 + sc * 8,
                &Bs[p][(it * 512 + wid * 64) * 8]);
    }
  };

  stage(0, 0);
  __syncthreads();
  for (int kb = 0; kb < 54; ++kb) {
    const int p = kb & 1;
    if (kb < 53) stage(kb + 1, p ^ 1);  // issue next-tile loads (async)
#pragma unroll
    for (int ks = 0; ks < 2; ++ks) {
      const int sk = ((ks * 4 + hi) ^ (r & 7)) << 3;
      bf16x8 af = *(const bf16x8*)&As[p][(wr * 16 + r) * 64 + sk];
      bf16x8 bfv[2];
#pragma unroll
      for (int fn = 0; fn < 2; ++fn)
        bfv[fn] = *(const bf16x8*)&Bs[p][(wc * 32 + fn * 16 + r) * 64 + sk];
#pragma unroll
      for (int fn = 0; fn < 2; ++fn)
        acc[fn] = __builtin_amdgcn_mfma_f32_16x16x32_bf16(af, bfv[fn], acc[fn], 0, 0, 0);
    }
    __syncthreads();  // drains prefetch; next buffer ready
  }
#pragma unroll
  for (int fn = 0; fn < 2; ++fn) {
    const int col = wc * 32 + fn * 16 + r;
#pragma unroll
    for (int q = 0; q < 4; ++q) {
      const int row = bm * 32 + wr * 16 + hi * 4 + q;
      int bb = row >> 11, t = row & 2047;
      dpad[((size_t)(bb * DROWS + PADR + t)) * 128 + col] = f2bf(acc[fn][q]);
    }
  }
}

// Spectral conv as block-Toeplitz GEMM (proven best: BM=128, 2-slot A-ring,
// 256 threads / 4 waves, 5 blocks/CU) + XCD-aware partition: each XCD owns a
// 6-kc x 4-b slice so its L2 holds T-slice (1.6MB) + hlnT-slice (2MB).
// Longest t-tiles first. xtc[b][t][kc*128 + d] (ld 3456)
__global__ __launch_bounds__(256) void gemm_conv(
    const u16* __restrict__ T, const u16* __restrict__ hlnT,
    u16* __restrict__ xtc) {
  __shared__ u16 As[2][64 * 64];
  __shared__ u16 Bs[128 * 64];
  const int tid = threadIdx.x;
  const int wid = tid >> 6, lane = tid & 63;
  const int xcd = blockIdx.x & 7;
  const int slot = blockIdx.x >> 3;        // 0..383
  const int tt = slot / 24;                // 0 => longest (t0 = 1920)
  const int rem24 = slot % 24;
  const int kc = (xcd >> 1) * 6 + rem24 % 6;
  const int b = (xcd & 1) * 4 + rem24 / 6;
  const int t0 = (15 - tt) << 7;
  const int r = lane & 15, hi = lane >> 4;
  const int wr = wid >> 1, wc = wid & 1;

  f32x4 acc[4][4];
#pragma unroll
  for (int i = 0; i < 4; ++i)
#pragma unroll
    for (int j = 0; j < 4; ++j) acc[i][j] = (f32x4){0.f, 0.f, 0.f, 0.f};

  const u16* Tk = T + (size_t)kc * 33 * 4096;
  const u16* Bb = hlnT + (size_t)b * 128 * 2048;
  const int base = t0 >> 6;
  const int nsb = base + 2;

  for (int sb = 0; sb < nsb; ++sb) {
    const int dlt = base - sb;
    const int p = sb & 1;
    if (sb) __syncthreads();
    // stage NEW low tile (ti = dlt+1) into As[p]
#pragma unroll
    for (int it = 0; it < 2; ++it) {
      int ci = it * 256 + tid;
      int sc = (ci & 7) ^ ((ci >> 3) & 7);
      gld_lds16(Tk + (size_t)(dlt + 1) * 4096 + (ci >> 3) * 64 + sc * 8,
                &As[p][(it * 256 + wid * 64) * 8]);
    }
    if (sb == 0) {
      // initial high tile (ti = dlt+2) into As[1]
#pragma unroll
      for (int it = 0; it < 2; ++it) {
        int ci = it * 256 + tid;
        int sc = (ci & 7) ^ ((ci >> 3) & 7);
        gld_lds16(Tk + (size_t)(dlt + 2) * 4096 + (ci >> 3) * 64 + sc * 8,
                  &As[1][(it * 256 + wid * 64) * 8]);
      }
    }
#pragma unroll
    for (int it = 0; it < 4; ++it) {
      int ci = it * 256 + tid;
      int sc = (ci & 7) ^ ((ci >> 3) & 7);
      gld_lds16(Bb + (size_t)(ci >> 3) * 2048 + sb * 64 + sc * 8,
                &Bs[(it * 256 + wid * 64) * 8]);
    }
    __syncthreads();
    // wave wr=0 reads rows 0-63 (tile dlt+1, As[p]); wr=1 reads As[p^1]
    const u16* Aw = As[p ^ wr];
#pragma unroll
    for (int ks = 0; ks < 2; ++ks) {
      const int sk = ((ks * 4 + hi) ^ (r & 7)) << 3;
      bf16x8 af[4], bfv[4];
#pragma unroll
      for (int fm = 0; fm < 4; ++fm)
        af[fm] = *(const bf16x8*)&Aw[(fm * 16 + r) * 64 + sk];
#pragma unroll
      for (int fn = 0; fn < 4; ++fn)
        bfv[fn] = *(const bf16x8*)&Bs[(wc * 64 + fn * 16 + r) * 64 + sk];
#pragma unroll
      for (int fm = 0; fm < 4; ++fm)
#pragma unroll
        for (int fn = 0; fn < 4; ++fn)
          acc[fm][fn] = __builtin_amdgcn_mfma_f32_16x16x32_bf16(
              af[fm], bfv[fn], acc[fm][fn], 0, 0, 0);
    }
  }
#pragma unroll
  for (int fm = 0; fm < 4; ++fm) {
#pragma unroll
    for (int fn = 0; fn < 4; ++fn) {
      const int col = wc * 64 + fn * 16 + r;
#pragma unroll
      for (int q = 0; q < 4; ++q) {
        const int row = t0 + wr * 64 + fm * 16 + hi * 4 + q;
        xtc[((size_t)(b * 2048 + row)) * 3456 + kc * 128 + col] = f2bf(acc[fm][fn][q]);
      }
    }
  }
}

// y-conv: y[t] = sum_tau H[tau] delta[t-tau]; banded block-Toeplitz over dpad.
// BK=128 (one full tap per stage). Epilogue: ybf = bf16(gelu(y)).
__global__ __launch_bounds__(256) void gemm_yconv(
    const u16* __restrict__ dpad, const u16* __restrict__ Hp,
    u16* __restrict__ ybf) {
  __shared__ u16 As[64 * 128];
  __shared__ u16 Bs[64 * 128];
  const int tid = threadIdx.x;
  const int wid = tid >> 6, lane = tid & 63;
  const int bm = blockIdx.x, bn = blockIdx.y;
  const int b = bm >> 5, t0 = (bm & 31) << 6;
  const int r = lane & 15, hi = lane >> 4;

  f32x4 acc[4];
#pragma unroll
  for (int j = 0; j < 4; ++j) acc[j] = (f32x4){0.f, 0.f, 0.f, 0.f};

  const u16* Ab = dpad + (size_t)b * DROWS * 128;
  for (int tap = 0; tap < TAPS; ++tap) {
    const u16* Ap = Ab + (size_t)(PADR + t0 - tap) * 128;
    if (tap) __syncthreads();
#pragma unroll
    for (int it = 0; it < 4; ++it) {
      int ci = it * 256 + tid;
      int row = ci >> 4;
      int sc = (ci & 15) ^ (row & 7);
      gld_lds16(Ap + (size_t)row * 128 + sc * 8,
                &As[(it * 256 + wid * 64) * 8]);
    }
#pragma unroll
    for (int it = 0; it < 4; ++it) {
      int ci = it * 256 + tid;
      int row = ci >> 4;
      int sc = (ci & 15) ^ (row & 7);
      gld_lds16(Hp + (size_t)(bn * 64 + row) * (TAPS * 128) + tap * 128 + sc * 8,
                &Bs[(it * 256 + wid * 64) * 8]);
    }
    __syncthreads();
#pragma unroll
    for (int ks = 0; ks < 4; ++ks) {
      const int sk = ((ks * 4 + hi) ^ (r & 7)) << 3;
      bf16x8 af = *(const bf16x8*)&As[(wid * 16 + r) * 128 + sk];
      bf16x8 bfv[4];
#pragma unroll
      for (int fn = 0; fn < 4; ++fn)
        bfv[fn] = *(const bf16x8*)&Bs[(fn * 16 + r) * 128 + sk];
#pragma unroll
      for (int fn = 0; fn < 4; ++fn)
        acc[fn] = __builtin_amdgcn_mfma_f32_16x16x32_bf16(af, bfv[fn], acc[fn], 0, 0, 0);
    }
  }
#pragma unroll
  for (int fn = 0; fn < 4; ++fn) {
    const int col = bn * 64 + fn * 16 + r;
#pragma unroll
    for (int q = 0; q < 4; ++q) {
      const int row = t0 + wid * 16 + hi * 4 + q;
      float v = acc[fn][q];
      float gl = 0.5f * v * (1.f + erff(v * 0.70710678118654752f));
      ybf[((size_t)(b * 2048 + row)) * 128 + col] = f2bf(gl);
    }
  }
}

// w1 GEMM (BM=32, BN=256, grid 512) with fused GLU + residual epilogue.
__global__ __launch_bounds__(256) void gemm_w1glu(
    const u16* __restrict__ ybf, const u16* __restrict__ w1T,
    const float* __restrict__ b1, float* __restrict__ h,
    u16* __restrict__ hbf) {
  __shared__ u16 As[32 * 64];
  __shared__ u16 Bs[256 * 64];
  __shared__ float sg[32][128];
  const int tid = threadIdx.x;
  const int wid = tid >> 6, lane = tid & 63;
  const int bm = blockIdx.x;
  const int wr = wid >> 1, wc = wid & 1;  // WTM=16, WTN=128
  const int r = lane & 15, hi = lane >> 4;

  f32x4 acc[8];
#pragma unroll
  for (int j = 0; j < 8; ++j) acc[j] = (f32x4){0.f, 0.f, 0.f, 0.f};

  for (int kb = 0; kb < 2; ++kb) {
    if (kb) __syncthreads();
    {
      int ci = tid;
      int sc = (ci & 7) ^ ((ci >> 3) & 7);
      gld_lds16(ybf + (size_t)(bm * 32 + (ci >> 3)) * 128 + kb * 64 + sc * 8,
                &As[(wid * 64) * 8]);
    }
#pragma unroll
    for (int it = 0; it < 8; ++it) {
      int ci = it * 256 + tid;
      int sc = (ci & 7) ^ ((ci >> 3) & 7);
      gld_lds16(w1T + (size_t)(ci >> 3) * 128 + kb * 64 + sc * 8,
                &Bs[(it * 256 + wid * 64) * 8]);
    }
    __syncthreads();
#pragma unroll
    for (int ks = 0; ks < 2; ++ks) {
      const int sk = ((ks * 4 + hi) ^ (r & 7)) << 3;
      bf16x8 af = *(const bf16x8*)&As[(wr * 16 + r) * 64 + sk];
      bf16x8 bfv[8];
#pragma unroll
      for (int fn = 0; fn < 8; ++fn)
        bfv[fn] = *(const bf16x8*)&Bs[(wc * 128 + fn * 16 + r) * 64 + sk];
#pragma unroll
      for (int fn = 0; fn < 8; ++fn)
        acc[fn] = __builtin_amdgcn_mfma_f32_16x16x32_bf16(af, bfv[fn], acc[fn], 0, 0, 0);
    }
  }
  __syncthreads();
  if (wc == 1) {
#pragma unroll
    for (int fn = 0; fn < 8; ++fn) {
      const int colg = fn * 16 + r;
      const float bv = b1[128 + colg];
#pragma unroll
      for (int q = 0; q < 4; ++q) {
        const int rl = wr * 16 + hi * 4 + q;
        float v = acc[fn][q] + bv;
        sg[rl][colg] = 1.f / (1.f + expf(-v));
      }
    }
  }
  __syncthreads();
  if (wc == 0) {
#pragma unroll
    for (int fn = 0; fn < 8; ++fn) {
      const int col = fn * 16 + r;
      const float bv = b1[col];
#pragma unroll
      for (int q = 0; q < 4; ++q) {
        const int rl = wr * 16 + hi * 4 + q;
        const size_t row = (size_t)bm * 32 + rl;
        float a = acc[fn][q] + bv;
        float hn = a * sg[rl][col] + h[row * 128 + col];
        h[row * 128 + col] = hn;
        hbf[row * 128 + col] = f2bf(hn);
      }
    }
  }
}

// ---------------- host ----------------

extern "C" void kernel_launch(void* const* d_in, const int* in_sizes, int n_in,
                              void* d_out, int out_size, void* d_ws, size_t ws_size,
                              hipStream_t stream) {
  (void)in_sizes; (void)n_in; (void)out_size; (void)ws_size;
  const float* x = (const float*)d_in[0];
  const float* emb_w = (const float*)d_in[1];
  const float* emb_b = (const float*)d_in[2];
  const float* ln_g = (const float*)d_in[3];
  const float* ln_b = (const float*)d_in[4];
  const float* m_phi = (const float*)d_in[5];
  const float* m_u = (const float*)d_in[6];
  const float* m_y = (const float*)d_in[7];
  const float* w1 = (const float*)d_in[8];
  const float* b1 = (const float*)d_in[9];
  const float* proj_w = (const float*)d_in[10];
  const float* proj_b = (const float*)d_in[11];
  const float* evals = (const float*)d_in[12];
  const float* evec = (const float*)d_in[13];
  float* out = (float*)d_out;

  char* p = (char*)d_ws;
  auto carve = [&](size_t bytes) {
    char* r = p;
    p += (bytes + 255) & ~(size_t)255;
    return r;
  };
  u16* Tbuf = (u16*)carve((size_t)24 * 33 * 4096 * 2);
  u16* embT = (u16*)carve(128 * 128 * 2);
  u16* w1T = (u16*)carve((size_t)2 * 256 * 128 * 2);
  u16* projT = (u16*)carve(64 * 128 * 2);
  u16* mphiT = (u16*)carve((size_t)2 * 128 * 3456 * 2);
  u16* Hp = (u16*)carve((size_t)2 * 128 * TAPS * 128 * 2);
  u16* xbf = (u16*)carve((size_t)ROWS * 128 * 2);
  float* h = (float*)carve((size_t)ROWS * 128 * 4);
  u16* hbf = (u16*)carve((size_t)ROWS * 128 * 2);
  u16* hlnT = (u16*)carve((size_t)ROWS * 128 * 2);
  u16* xtc = (u16*)carve((size_t)ROWS * 3456 * 2);
  u16* dpad = (u16*)carve((size_t)8 * DROWS * 128 * 2);
  u16* ybf = (u16*)carve((size_t)ROWS * 128 * 2);

  hprep_kernel<<<dim3(256), dim3(128), 0, stream>>>(m_y, Hp);
  prep_misc<<<dim3(6681), dim3(256), 0, stream>>>(
      emb_w, w1, proj_w, m_phi, m_u, x, evec, evals,
      embT, w1T, projT, mphiT, xbf, dpad, xtc, Tbuf);

  // h = x @ emb_w + emb_b
  gemm_bt<32, 128, 2, 2><<<dim3(512, 1), dim3(256), 0, stream>>>(
      xbf, 128, embT, 128, h, 128, emb_b, 2);

  for (int l = 0; l < 2; ++l) {
    const u16* mT = mphiT + (size_t)l * 128 * 3456;
    ln_tr_kernel<<<dim3(256), dim3(256), 0, stream>>>(
        h, ln_g + l * 128, ln_b + l * 128, hlnT, xtc);
    gemm_conv<<<dim3(3072), dim3(256), 0, stream>>>(Tbuf, hlnT, xtc);
    gemm_delta<<<dim3(512), dim3(512), 0, stream>>>(xtc, mT, dpad);
    gemm_yconv<<<dim3(256, 2), dim3(256), 0, stream>>>(
        dpad, Hp + (size_t)l * 128 * TAPS * 128, ybf);
    gemm_w1glu<<<dim3(512), dim3(256), 0, stream>>>(
        ybf, w1T + (size_t)l * 256 * 128, b1 + l * 256, h, hbf);
  }

  // out = h @ proj_w + proj_b
  gemm_bt<32, 64, 2, 2><<<dim3(512, 1), dim3(256), 0, stream>>>(
      hbf, 128, projT, 128, out, 64, proj_b, 2);
}